// Round 2
// baseline (2105.868 us; speedup 1.0000x reference)
//
#include <hip/hip_runtime.h>
#include <hip/hip_bf16.h>

#define NN 50000
#define NE 800000
#define DD 64
#define NEG 0.2f

// ---------------- CSR build ----------------
__global__ void k_hist(const int* __restrict__ dst1, const int* __restrict__ dst2,
                       int* __restrict__ cnt1, int* __restrict__ cnt2) {
    int e = blockIdx.x * blockDim.x + threadIdx.x;
    if (e < NE) {
        atomicAdd(&cnt1[dst1[e]], 1);
        atomicAdd(&cnt2[dst2[e]], 1);
    }
}

__global__ __launch_bounds__(1024) void k_scan(const int* __restrict__ cnt1, int* __restrict__ off1,
                                               const int* __restrict__ cnt2, int* __restrict__ off2) {
    const int* cnt = blockIdx.x ? cnt2 : cnt1;
    int* off = blockIdx.x ? off2 : off1;
    __shared__ int lds[1024];
    const int tid = threadIdx.x;
    const int CH = (NN + 1023) / 1024;  // 49
    const int base = tid * CH;
    int s = 0;
    for (int q = 0; q < CH; ++q) {
        int idx = base + q;
        if (idx < NN) s += cnt[idx];
    }
    lds[tid] = s;
    __syncthreads();
    // Hillis-Steele inclusive scan
    for (int d = 1; d < 1024; d <<= 1) {
        int v = (tid >= d) ? lds[tid - d] : 0;
        __syncthreads();
        lds[tid] += v;
        __syncthreads();
    }
    int run = tid ? lds[tid - 1] : 0;  // exclusive prefix of this chunk
    for (int q = 0; q < CH; ++q) {
        int idx = base + q;
        if (idx < NN) { off[idx] = run; run += cnt[idx]; }
    }
    if (tid == 1023) off[NN] = lds[1023];
}

__global__ void k_scatter(const int* __restrict__ src1, const int* __restrict__ dst1,
                          const int* __restrict__ off1, int* __restrict__ fill1, int* __restrict__ csr1,
                          const int* __restrict__ src2, const int* __restrict__ dst2,
                          const int* __restrict__ off2, int* __restrict__ fill2, int* __restrict__ csr2) {
    int e = blockIdx.x * blockDim.x + threadIdx.x;
    if (e < NE) {
        int d1 = dst1[e];
        int p1 = off1[d1] + atomicAdd(&fill1[d1], 1);
        csr1[p1] = src1[e];
        int d2 = dst2[e];
        int p2 = off2[d2] + atomicAdd(&fill2[d2], 1);
        csr2[p2] = src2[e];
    }
}

// ---------------- H1 = x @ W1 (once), alpha1 = H1 @ a1_{src,dst} ----------------
__global__ __launch_bounds__(256) void k_h1(
    const float* __restrict__ x, const float* __restrict__ W1,
    const float* __restrict__ a1s, const float* __restrict__ a1d,
    float* __restrict__ H1, float* __restrict__ al1s, float* __restrict__ al1d) {
    const int lane = threadIdx.x & 63;
    const int i = blockIdx.x * 4 + (threadIdx.x >> 6);
    float wcol[DD];
#pragma unroll
    for (int k = 0; k < DD; ++k) wcol[k] = W1[k * DD + lane];
    const float asv = a1s[lane];
    const float adv = a1d[lane];
    const float xv = x[i * DD + lane];
    float h = 0.f;
#pragma unroll
    for (int k = 0; k < DD; ++k) h = fmaf(__shfl(xv, k), wcol[k], h);
    H1[i * DD + lane] = h;
    float ps = h * asv, pd = h * adv;
#pragma unroll
    for (int o = 32; o; o >>= 1) { ps += __shfl_xor(ps, o); pd += __shfl_xor(pd, o); }
    if (lane == 0) { al1s[i] = ps; al1d[i] = pd; }
}

// ---------------- per step: layer1 aggregate + ELU + @W2 + alpha2 ----------------
__global__ __launch_bounds__(256) void k_layer1(
    const int* __restrict__ off, const int* __restrict__ csrc,
    const float* __restrict__ al1s, const float* __restrict__ al1d,
    const float* __restrict__ H1,
    const float* __restrict__ W2, const float* __restrict__ a2s, const float* __restrict__ a2d,
    float* __restrict__ H2, float* __restrict__ al2s, float* __restrict__ al2d, float t) {
    const int lane = threadIdx.x & 63;
    const int i = blockIdx.x * 4 + (threadIdx.x >> 6);
    float wcol[DD];
#pragma unroll
    for (int k = 0; k < DD; ++k) wcol[k] = W2[k * DD + lane];
    const float a2sv = a2s[lane];
    const float a2dv = a2d[lane];

    const int p0 = off[i], p1 = off[i + 1];
    const float adv = al1d[i];
    float num = 0.f, den = 0.f;
    for (int p = p0; p < p1; ++p) {
        int s = csrc[p];
        float z = al1s[s] + adv;
        float lr = z > 0.f ? z : NEG * z;
        float w = __expf(t * lr);
        den += w;
        num = fmaf(w, H1[s * DD + lane], num);
    }
    float hm = (den > 0.f) ? (t * num / den) : 0.f;
    hm = (hm > 0.f) ? hm : expm1f(hm);  // ELU

    float h2 = 0.f;
#pragma unroll
    for (int k = 0; k < DD; ++k) h2 = fmaf(__shfl(hm, k), wcol[k], h2);
    H2[i * DD + lane] = h2;
    float ps = h2 * a2sv, pd = h2 * a2dv;
#pragma unroll
    for (int o = 32; o; o >>= 1) { ps += __shfl_xor(ps, o); pd += __shfl_xor(pd, o); }
    if (lane == 0) { al2s[i] = ps; al2d[i] = pd; }
}

// ---------------- per step: layer2 aggregate, accumulate into out ----------------
__global__ __launch_bounds__(256) void k_layer2(
    const int* __restrict__ off, const int* __restrict__ csrc,
    const float* __restrict__ al2s, const float* __restrict__ al2d,
    const float* __restrict__ H2, float* __restrict__ acc) {
    const int lane = threadIdx.x & 63;
    const int i = blockIdx.x * 4 + (threadIdx.x >> 6);
    const int p0 = off[i], p1 = off[i + 1];
    const float adv = al2d[i];
    float num = 0.f, den = 0.f;
    for (int p = p0; p < p1; ++p) {
        int s = csrc[p];
        float z = al2s[s] + adv;
        float lr = z > 0.f ? z : NEG * z;
        float w = __expf(lr);
        den += w;
        num = fmaf(w, H2[s * DD + lane], num);
    }
    float o = (den > 0.f) ? (num / den) : 0.f;
    acc[i * DD + lane] += o;
}

__global__ void k_final(float* __restrict__ acc) {
    int idx = blockIdx.x * blockDim.x + threadIdx.x;
    acc[idx] *= (1.f / 9.f);
}

extern "C" void kernel_launch(void* const* d_in, const int* in_sizes, int n_in,
                              void* d_out, int out_size, void* d_ws, size_t ws_size,
                              hipStream_t stream) {
    const float* x   = (const float*)d_in[0];
    const int*   ei1 = (const int*)d_in[1];
    const int*   ei2 = (const int*)d_in[2];
    const float* W1  = (const float*)d_in[3];
    const float* a1s = (const float*)d_in[4];
    const float* a1d = (const float*)d_in[5];
    const float* W2  = (const float*)d_in[6];
    const float* a2s = (const float*)d_in[7];
    const float* a2d = (const float*)d_in[8];
    float* out = (float*)d_out;   // used as fp32 accumulator across the 9 steps

    const int* src1 = ei1;          // edge_index[0]
    const int* dst1 = ei1 + NE;     // edge_index[1]
    const int* src2 = ei2;
    const int* dst2 = ei2 + NE;

    // workspace layout (all 4-byte elements), ~34 MB total
    float* H1   = (float*)d_ws;          // NN*DD
    float* H2   = H1 + NN * DD;          // NN*DD
    float* al1s = H2 + NN * DD;          // NN
    float* al1d = al1s + NN;             // NN
    float* al2s = al1d + NN;             // NN
    float* al2d = al2s + NN;             // NN
    int* off1 = (int*)(al2d + NN);       // NN+1
    int* off2 = off1 + (NN + 1);         // NN+1
    int* cnt1 = off2 + (NN + 1);         // NN
    int* cnt2 = cnt1 + NN;               // NN  (cnt1,cnt2 contiguous)
    int* csr1 = cnt2 + NN;               // NE
    int* csr2 = csr1 + NE;               // NE

    const int EB = 256, EG = (NE + EB - 1) / EB;

    hipMemsetAsync(cnt1, 0, 2 * NN * sizeof(int), stream);
    hipMemsetAsync(out, 0, (size_t)NN * DD * sizeof(float), stream);
    k_hist<<<EG, EB, 0, stream>>>(dst1, dst2, cnt1, cnt2);
    k_scan<<<2, 1024, 0, stream>>>(cnt1, off1, cnt2, off2);
    hipMemsetAsync(cnt1, 0, 2 * NN * sizeof(int), stream);
    k_scatter<<<EG, EB, 0, stream>>>(src1, dst1, off1, cnt1, csr1,
                                     src2, dst2, off2, cnt2, csr2);

    const int NB = NN / 4;  // 12500 blocks, wave-per-node
    k_h1<<<NB, 256, 0, stream>>>(x, W1, a1s, a1d, H1, al1s, al1d);

    for (int k = 1; k <= 9; ++k) {
        float t = (float)k / 9.0f;
        k_layer1<<<NB, 256, 0, stream>>>(off1, csr1, al1s, al1d, H1,
                                         W2, a2s, a2d, H2, al2s, al2d, t);
        k_layer2<<<NB, 256, 0, stream>>>(off2, csr2, al2s, al2d, H2, out);
    }

    k_final<<<(NN * DD) / 256, 256, 0, stream>>>(out);
}

// Round 3
// 1107.790 us; speedup vs baseline: 1.9010x; 1.9010x over previous
//
#include <hip/hip_runtime.h>
#include <hip/hip_bf16.h>

#define NN 50000
#define NE 800000
#define DD 64
#define NEG 0.2f
#define MAXK 9

// ---------------- CSR build ----------------
__global__ void k_hist(const int* __restrict__ dst1, const int* __restrict__ dst2,
                       int* __restrict__ cnt1, int* __restrict__ cnt2) {
    int e = blockIdx.x * blockDim.x + threadIdx.x;
    if (e < NE) {
        atomicAdd(&cnt1[dst1[e]], 1);
        atomicAdd(&cnt2[dst2[e]], 1);
    }
}

__global__ __launch_bounds__(1024) void k_scan(const int* __restrict__ cnt1, int* __restrict__ off1,
                                               const int* __restrict__ cnt2, int* __restrict__ off2) {
    const int* cnt = blockIdx.x ? cnt2 : cnt1;
    int* off = blockIdx.x ? off2 : off1;
    __shared__ int lds[1024];
    const int tid = threadIdx.x;
    const int CH = (NN + 1023) / 1024;  // 49
    const int base = tid * CH;
    int s = 0;
    for (int q = 0; q < CH; ++q) {
        int idx = base + q;
        if (idx < NN) s += cnt[idx];
    }
    lds[tid] = s;
    __syncthreads();
    for (int d = 1; d < 1024; d <<= 1) {
        int v = (tid >= d) ? lds[tid - d] : 0;
        __syncthreads();
        lds[tid] += v;
        __syncthreads();
    }
    int run = tid ? lds[tid - 1] : 0;
    for (int q = 0; q < CH; ++q) {
        int idx = base + q;
        if (idx < NN) { off[idx] = run; run += cnt[idx]; }
    }
    if (tid == 1023) off[NN] = lds[1023];
}

__global__ void k_scatter(const int* __restrict__ src1, const int* __restrict__ dst1,
                          const int* __restrict__ off1, int* __restrict__ fill1, int* __restrict__ csr1,
                          const int* __restrict__ src2, const int* __restrict__ dst2,
                          const int* __restrict__ off2, int* __restrict__ fill2, int* __restrict__ csr2) {
    int e = blockIdx.x * blockDim.x + threadIdx.x;
    if (e < NE) {
        int d1 = dst1[e];
        int p1 = off1[d1] + atomicAdd(&fill1[d1], 1);
        csr1[p1] = src1[e];
        int d2 = dst2[e];
        int p2 = off2[d2] + atomicAdd(&fill2[d2], 1);
        csr2[p2] = src2[e];
    }
}

// ---------------- H1 = x @ W1 (once), alpha1 = H1 @ a1_{src,dst} ----------------
__global__ __launch_bounds__(256) void k_h1(
    const float* __restrict__ x, const float* __restrict__ W1,
    const float* __restrict__ a1s, const float* __restrict__ a1d,
    float* __restrict__ H1, float* __restrict__ al1s, float* __restrict__ al1d) {
    const int lane = threadIdx.x & 63;
    const int i = blockIdx.x * 4 + (threadIdx.x >> 6);
    float wcol[DD];
#pragma unroll
    for (int k = 0; k < DD; ++k) wcol[k] = W1[k * DD + lane];
    const float asv = a1s[lane];
    const float adv = a1d[lane];
    const float xv = x[i * DD + lane];
    float h = 0.f;
#pragma unroll
    for (int k = 0; k < DD; ++k) h = fmaf(__shfl(xv, k), wcol[k], h);
    H1[i * DD + lane] = h;
    float ps = h * asv, pd = h * adv;
#pragma unroll
    for (int o = 32; o; o >>= 1) { ps += __shfl_xor(ps, o); pd += __shfl_xor(pd, o); }
    if (lane == 0) { al1s[i] = ps; al1d[i] = pd; }
}

// ---- layer1 for nk steps at once: aggregate + ELU + @W2 + alpha2 ----
// steps are global indices k0+1 .. k0+nk (t = step/9)
__global__ __launch_bounds__(256) void k_layer1_all(
    const int* __restrict__ off, const int* __restrict__ csrc,
    const float* __restrict__ al1s, const float* __restrict__ al1d,
    const float* __restrict__ H1,
    const float* __restrict__ W2, const float* __restrict__ a2s, const float* __restrict__ a2d,
    _Float16* __restrict__ H2h, float* __restrict__ al2s, float* __restrict__ al2d,
    int k0, int nk) {
    const int lane = threadIdx.x & 63;
    const int i = blockIdx.x * 4 + (threadIdx.x >> 6);
    float wcol[DD];
#pragma unroll
    for (int k = 0; k < DD; ++k) wcol[k] = W2[k * DD + lane];
    const float a2sv = a2s[lane];
    const float a2dv = a2d[lane];

    const int p0 = off[i], p1 = off[i + 1];
    const float adv = al1d[i];
    float num[MAXK], den[MAXK];
#pragma unroll
    for (int k = 0; k < MAXK; ++k) { num[k] = 0.f; den[k] = 0.f; }

    for (int p = p0; p < p1; ++p) {
        int s = __ldg(&csrc[p]);
        float z = al1s[s] + adv;
        float c = z > 0.f ? z : NEG * z;          // leaky_relu, step-invariant
        float r = __expf(c * (1.f / 9.f));        // exp(t_k*c) = r^k
        float w = r;
        for (int q = 0; q < k0; ++q) w *= r;      // start at step k0+1
        float hv = H1[s * DD + lane];
#pragma unroll
        for (int k = 0; k < MAXK; ++k) {
            if (k < nk) {
                den[k] += w;
                num[k] = fmaf(w, hv, num[k]);
                w *= r;
            }
        }
    }

#pragma unroll
    for (int k = 0; k < MAXK; ++k) {
        if (k < nk) {
            float t = (float)(k0 + k + 1) * (1.f / 9.f);
            float hm = (den[k] > 0.f) ? (t * num[k] / den[k]) : 0.f;
            hm = (hm > 0.f) ? hm : expm1f(hm);    // ELU
            float h2 = 0.f;
#pragma unroll
            for (int j = 0; j < DD; ++j) h2 = fmaf(__shfl(hm, j), wcol[j], h2);
            H2h[((size_t)i * nk + k) * DD + lane] = (_Float16)h2;
            float ps = h2 * a2sv, pd = h2 * a2dv;
#pragma unroll
            for (int o = 32; o; o >>= 1) { ps += __shfl_xor(ps, o); pd += __shfl_xor(pd, o); }
            if (lane == 0) { al2s[(size_t)i * nk + k] = ps; al2d[(size_t)i * nk + k] = pd; }
        }
    }
}

// ---- layer2 for nk steps at once: aggregate, sum over steps into out ----
__global__ __launch_bounds__(256) void k_layer2_all(
    const int* __restrict__ off, const int* __restrict__ csrc,
    const float* __restrict__ al2s, const float* __restrict__ al2d,
    const _Float16* __restrict__ H2h, float* __restrict__ out,
    int nk, int first) {
    const int lane = threadIdx.x & 63;
    const int i = blockIdx.x * 4 + (threadIdx.x >> 6);
    const int p0 = off[i], p1 = off[i + 1];
    float adv[MAXK], num[MAXK], den[MAXK];
#pragma unroll
    for (int k = 0; k < MAXK; ++k) {
        num[k] = 0.f; den[k] = 0.f;
        adv[k] = (k < nk) ? al2d[(size_t)i * nk + k] : 0.f;
    }
    for (int p = p0; p < p1; ++p) {
        int s = __ldg(&csrc[p]);
        const _Float16* hrow = H2h + (size_t)s * nk * DD + lane;
        const float* als = al2s + (size_t)s * nk;
#pragma unroll
        for (int k = 0; k < MAXK; ++k) {
            if (k < nk) {
                float z = als[k] + adv[k];
                float lr = z > 0.f ? z : NEG * z;
                float w = __expf(lr);
                float h = (float)hrow[k * DD];
                den[k] += w;
                num[k] = fmaf(w, h, num[k]);
            }
        }
    }
    float o = 0.f;
#pragma unroll
    for (int k = 0; k < MAXK; ++k)
        if (k < nk) o += (den[k] > 0.f) ? (num[k] / den[k]) : 0.f;
    o *= (1.f / 9.f);
    if (first) out[i * DD + lane] = o;
    else       out[i * DD + lane] += o;
}

extern "C" void kernel_launch(void* const* d_in, const int* in_sizes, int n_in,
                              void* d_out, int out_size, void* d_ws, size_t ws_size,
                              hipStream_t stream) {
    const float* x   = (const float*)d_in[0];
    const int*   ei1 = (const int*)d_in[1];
    const int*   ei2 = (const int*)d_in[2];
    const float* W1  = (const float*)d_in[3];
    const float* a1s = (const float*)d_in[4];
    const float* a1d = (const float*)d_in[5];
    const float* W2  = (const float*)d_in[6];
    const float* a2s = (const float*)d_in[7];
    const float* a2d = (const float*)d_in[8];
    float* out = (float*)d_out;

    const int* src1 = ei1;
    const int* dst1 = ei1 + NE;
    const int* src2 = ei2;
    const int* dst2 = ei2 + NE;

    // ---- workspace layout (4-byte words) ----
    float* H1   = (float*)d_ws;          // NN*DD
    float* al1s = H1 + (size_t)NN * DD;  // NN
    float* al1d = al1s + NN;             // NN
    int* off1 = (int*)(al1d + NN);       // NN+1
    int* off2 = off1 + (NN + 1);         // NN+1
    int* cnt1 = off2 + (NN + 1);         // NN
    int* cnt2 = cnt1 + NN;               // NN (cnt1,cnt2 contiguous for one memset)
    int* csr1 = cnt2 + NN;               // NE
    int* csr2 = csr1 + NE;               // NE
    float* chunkBase = (float*)(csr2 + NE);

    size_t fixedWords = (size_t)NN * DD + 2 * NN + 2 * (NN + 1) + 2 * NN + 2 * (size_t)NE;
    size_t availWords = ws_size / 4 > fixedWords ? ws_size / 4 - fixedWords : 0;
    // per step: al2s(NN) + al2d(NN) + H2h(NN*DD halves = NN*DD/2 words)
    size_t perStep = (size_t)NN * 2 + (size_t)NN * DD / 2;
    int nk_max = (int)(availWords / perStep);
    if (nk_max > MAXK) nk_max = MAXK;
    if (nk_max < 1) nk_max = 1;  // requires ~7 MB beyond fixed; assume available

    const int EB = 256, EG = (NE + EB - 1) / EB;
    const int NB = NN / 4;

    hipMemsetAsync(cnt1, 0, 2 * NN * sizeof(int), stream);
    k_hist<<<EG, EB, 0, stream>>>(dst1, dst2, cnt1, cnt2);
    k_scan<<<2, 1024, 0, stream>>>(cnt1, off1, cnt2, off2);
    hipMemsetAsync(cnt1, 0, 2 * NN * sizeof(int), stream);
    k_scatter<<<EG, EB, 0, stream>>>(src1, dst1, off1, cnt1, csr1,
                                     src2, dst2, off2, cnt2, csr2);
    k_h1<<<NB, 256, 0, stream>>>(x, W1, a1s, a1d, H1, al1s, al1d);

    int done = 0;
    while (done < MAXK) {
        int nk = MAXK - done < nk_max ? MAXK - done : nk_max;
        float* al2s = chunkBase;                       // NN*nk
        float* al2d = al2s + (size_t)NN * nk;          // NN*nk
        _Float16* H2h = (_Float16*)(al2d + (size_t)NN * nk);  // NN*nk*DD halves
        k_layer1_all<<<NB, 256, 0, stream>>>(off1, csr1, al1s, al1d, H1,
                                             W2, a2s, a2d, H2h, al2s, al2d, done, nk);
        k_layer2_all<<<NB, 256, 0, stream>>>(off2, csr2, al2s, al2d, H2h, out,
                                             nk, done == 0 ? 1 : 0);
        done += nk;
    }
}

// Round 5
// 826.389 us; speedup vs baseline: 2.5483x; 1.3405x over previous
//
#include <hip/hip_runtime.h>
#include <hip/hip_bf16.h>

#define NN 50000
#define NE 800000
#define DD 64
#define NEG 0.2f

#define RFL(x) __builtin_amdgcn_readfirstlane(x)

// ---------------- CSR build ----------------
__global__ void k_hist(const int* __restrict__ dst1, const int* __restrict__ dst2,
                       int* __restrict__ cnt1, int* __restrict__ cnt2) {
    int e = blockIdx.x * blockDim.x + threadIdx.x;
    if (e < NE) {
        atomicAdd(&cnt1[dst1[e]], 1);
        atomicAdd(&cnt2[dst2[e]], 1);
    }
}

__global__ __launch_bounds__(1024) void k_scan(const int* __restrict__ cnt1, int* __restrict__ off1,
                                               const int* __restrict__ cnt2, int* __restrict__ off2) {
    const int* cnt = blockIdx.x ? cnt2 : cnt1;
    int* off = blockIdx.x ? off2 : off1;
    __shared__ int lds[1024];
    const int tid = threadIdx.x;
    const int CH = (NN + 1023) / 1024;  // 49
    const int base = tid * CH;
    int s = 0;
    for (int q = 0; q < CH; ++q) {
        int idx = base + q;
        if (idx < NN) s += cnt[idx];
    }
    lds[tid] = s;
    __syncthreads();
    for (int d = 1; d < 1024; d <<= 1) {
        int v = (tid >= d) ? lds[tid - d] : 0;
        __syncthreads();
        lds[tid] += v;
        __syncthreads();
    }
    int run = tid ? lds[tid - 1] : 0;
    for (int q = 0; q < CH; ++q) {
        int idx = base + q;
        if (idx < NN) { off[idx] = run; run += cnt[idx]; }
    }
    if (tid == 1023) off[NN] = lds[1023];
}

__global__ void k_scatter(const int* __restrict__ src1, const int* __restrict__ dst1,
                          const int* __restrict__ off1, int* __restrict__ fill1, int* __restrict__ csr1,
                          const int* __restrict__ src2, const int* __restrict__ dst2,
                          const int* __restrict__ off2, int* __restrict__ fill2, int* __restrict__ csr2) {
    int e = blockIdx.x * blockDim.x + threadIdx.x;
    if (e < NE) {
        int d1 = dst1[e];
        int p1 = off1[d1] + atomicAdd(&fill1[d1], 1);
        csr1[p1] = src1[e];
        int d2 = dst2[e];
        int p2 = off2[d2] + atomicAdd(&fill2[d2], 1);
        csr2[p2] = src2[e];
    }
}

// ---------------- H1 = x @ W1, alpha1 = H1 @ a1_{src,dst} ----------------
__global__ __launch_bounds__(256) void k_h1(
    const float* __restrict__ x, const float* __restrict__ W1,
    const float* __restrict__ a1s, const float* __restrict__ a1d,
    float* __restrict__ H1, float* __restrict__ al1s, float* __restrict__ al1d) {
    const int lane = threadIdx.x & 63;
    const int i = blockIdx.x * 4 + (threadIdx.x >> 6);
    float wcol[DD];
#pragma unroll
    for (int k = 0; k < DD; ++k) wcol[k] = W1[k * DD + lane];
    const float asv = a1s[lane];
    const float adv = a1d[lane];
    const float xv = x[i * DD + lane];
    float h = 0.f;
#pragma unroll
    for (int k = 0; k < DD; ++k) h = fmaf(__shfl(xv, k), wcol[k], h);
    H1[i * DD + lane] = h;
    float ps = h * asv, pd = h * adv;
#pragma unroll
    for (int o = 32; o; o >>= 1) { ps += __shfl_xor(ps, o); pd += __shfl_xor(pd, o); }
    if (lane == 0) { al1s[i] = ps; al1d[i] = pd; }
}

// ---- layer1, all 9 steps in one pass: aggregate + ELU + @W2 + alpha2 ----
// H2a: steps 1..8 packed [i][lane][k] as 8 halves (uint4); H2b: step 9 as half [i][lane]
__global__ __launch_bounds__(256) void k_l1(
    const int* __restrict__ off, const int* __restrict__ csrc,
    const float* __restrict__ al1s, const float* __restrict__ al1d,
    const float* __restrict__ H1,
    const float* __restrict__ W2, const float* __restrict__ a2s, const float* __restrict__ a2d,
    uint4* __restrict__ H2a, _Float16* __restrict__ H2b,
    float* __restrict__ al2s8, float* __restrict__ al2s9, float* __restrict__ al2d) {
    const int lane = threadIdx.x & 63;
    const int i = blockIdx.x * 4 + (threadIdx.x >> 6);
    float wcol[DD];
#pragma unroll
    for (int k = 0; k < DD; ++k) wcol[k] = W2[k * DD + lane];
    const float a2sv = a2s[lane];
    const float a2dv = a2d[lane];

    const int p0 = RFL(off[i]);
    const int p1 = RFL(off[i + 1]);
    const float adv = al1d[i];
    float num[9], den[9];
#pragma unroll
    for (int k = 0; k < 9; ++k) { num[k] = 0.f; den[k] = 0.f; }

    auto edge = [&](int s) {
        float hv = H1[(size_t)s * DD + lane];
        float z = al1s[s] + adv;
        float c = z > 0.f ? z : NEG * z;           // leaky_relu, step-invariant
        float r = __expf(c * (1.f / 9.f));         // w_k = r^k
        float w = r;
#pragma unroll
        for (int k = 0; k < 9; ++k) { den[k] += w; num[k] = fmaf(w, hv, num[k]); w *= r; }
    };
    int p = p0;
    for (; p + 1 < p1; p += 2) {
        int sA = RFL(csrc[p]);
        int sB = RFL(csrc[p + 1]);
        edge(sA);
        edge(sB);
    }
    if (p < p1) edge(RFL(csrc[p]));

    float h2all[9];
#pragma unroll
    for (int k = 0; k < 9; ++k) {
        float t = (float)(k + 1) * (1.f / 9.f);
        float hm = (den[k] > 0.f) ? (t * num[k] / den[k]) : 0.f;
        hm = (hm > 0.f) ? hm : expm1f(hm);         // ELU
        float h2 = 0.f;
#pragma unroll
        for (int j = 0; j < DD; ++j) h2 = fmaf(__shfl(hm, j), wcol[j], h2);
        h2all[k] = h2;
        float ps = h2 * a2sv, pd = h2 * a2dv;
#pragma unroll
        for (int o = 32; o; o >>= 1) { ps += __shfl_xor(ps, o); pd += __shfl_xor(pd, o); }
        if (lane == 0) {
            if (k < 8) al2s8[(size_t)i * 8 + k] = ps;
            else       al2s9[i] = ps;
            al2d[(size_t)i * 9 + k] = pd;
        }
    }
    union { _Float16 h[8]; uint4 u; } pk;
#pragma unroll
    for (int k = 0; k < 8; ++k) pk.h[k] = (_Float16)h2all[k];
    H2a[(size_t)i * DD + lane] = pk.u;
    H2b[(size_t)i * DD + lane] = (_Float16)h2all[8];
}

// ---- layer2, all 9 steps in one pass: aggregate, average into out ----
__global__ __launch_bounds__(256) void k_l2(
    const int* __restrict__ off, const int* __restrict__ csrc,
    const float* __restrict__ al2s8, const float* __restrict__ al2s9,
    const float* __restrict__ al2d,
    const uint4* __restrict__ H2a, const _Float16* __restrict__ H2b,
    float* __restrict__ out) {
    const int lane = threadIdx.x & 63;
    const int i = blockIdx.x * 4 + (threadIdx.x >> 6);
    const int p0 = RFL(off[i]);
    const int p1 = RFL(off[i + 1]);
    float adv[9];
#pragma unroll
    for (int k = 0; k < 9; ++k) adv[k] = al2d[(size_t)i * 9 + k];
    float num[9], den[9];
#pragma unroll
    for (int k = 0; k < 9; ++k) { num[k] = 0.f; den[k] = 0.f; }

    auto edge = [&](int s) {
        uint4 u = H2a[(size_t)s * DD + lane];
        float h9 = (float)H2b[(size_t)s * DD + lane];
        const float4* pa = (const float4*)(al2s8 + (size_t)s * 8);
        float4 A0 = pa[0], A1 = pa[1];
        float A9 = al2s9[s];
        union { uint4 v; _Float16 h[8]; } c; c.v = u;
        float as[8] = {A0.x, A0.y, A0.z, A0.w, A1.x, A1.y, A1.z, A1.w};
#pragma unroll
        for (int k = 0; k < 8; ++k) {
            float z = as[k] + adv[k];
            float lr = z > 0.f ? z : NEG * z;
            float w = __expf(lr);
            den[k] += w;
            num[k] = fmaf(w, (float)c.h[k], num[k]);
        }
        float z = A9 + adv[8];
        float lr = z > 0.f ? z : NEG * z;
        float w = __expf(lr);
        den[8] += w;
        num[8] = fmaf(w, h9, num[8]);
    };
    int p = p0;
    for (; p + 1 < p1; p += 2) {
        int sA = RFL(csrc[p]);
        int sB = RFL(csrc[p + 1]);
        edge(sA);
        edge(sB);
    }
    if (p < p1) edge(RFL(csrc[p]));

    float o = 0.f;
#pragma unroll
    for (int k = 0; k < 9; ++k) o += (den[k] > 0.f) ? (num[k] / den[k]) : 0.f;
    out[(size_t)i * DD + lane] = o * (1.f / 9.f);
}

extern "C" void kernel_launch(void* const* d_in, const int* in_sizes, int n_in,
                              void* d_out, int out_size, void* d_ws, size_t ws_size,
                              hipStream_t stream) {
    const float* x   = (const float*)d_in[0];
    const int*   ei1 = (const int*)d_in[1];
    const int*   ei2 = (const int*)d_in[2];
    const float* W1  = (const float*)d_in[3];
    const float* a1s = (const float*)d_in[4];
    const float* a1d = (const float*)d_in[5];
    const float* W2  = (const float*)d_in[6];
    const float* a2s = (const float*)d_in[7];
    const float* a2d = (const float*)d_in[8];
    float* out = (float*)d_out;

    const int* src1 = ei1;
    const int* dst1 = ei1 + NE;
    const int* src2 = ei2;
    const int* dst2 = ei2 + NE;

    // ---- workspace layout (4-byte words), ~81.6 MB total ----
    uint4* H2a   = (uint4*)d_ws;                          // NN*64 uint4 (51.2 MB)
    float* H1    = (float*)d_ws + (size_t)NN * 256;       // NN*DD
    float* al1s  = H1 + (size_t)NN * DD;                  // NN
    float* al1d  = al1s + NN;                             // NN
    float* al2s8 = al1d + NN;                             // NN*8
    float* al2s9 = al2s8 + (size_t)NN * 8;                // NN
    float* al2d  = al2s9 + NN;                            // NN*9
    _Float16* H2b = (_Float16*)(al2d + (size_t)NN * 9);   // NN*DD halves
    int* off1 = (int*)((float*)H2b + (size_t)NN * DD / 2);// NN+1
    int* off2 = off1 + (NN + 1);                          // NN+1
    int* cnt1 = off2 + (NN + 1);                          // NN
    int* cnt2 = cnt1 + NN;                                // NN (contiguous with cnt1)
    int* csr1 = cnt2 + NN;                                // NE
    int* csr2 = csr1 + NE;                                // NE

    const int EB = 256, EG = (NE + EB - 1) / EB;
    const int NB = NN / 4;  // wave per node

    hipMemsetAsync(cnt1, 0, 2 * NN * sizeof(int), stream);
    k_hist<<<EG, EB, 0, stream>>>(dst1, dst2, cnt1, cnt2);
    k_scan<<<2, 1024, 0, stream>>>(cnt1, off1, cnt2, off2);
    hipMemsetAsync(cnt1, 0, 2 * NN * sizeof(int), stream);
    k_scatter<<<EG, EB, 0, stream>>>(src1, dst1, off1, cnt1, csr1,
                                     src2, dst2, off2, cnt2, csr2);
    k_h1<<<NB, 256, 0, stream>>>(x, W1, a1s, a1d, H1, al1s, al1d);

    k_l1<<<NB, 256, 0, stream>>>(off1, csr1, al1s, al1d, H1,
                                 W2, a2s, a2d, H2a, H2b, al2s8, al2s9, al2d);
    k_l2<<<NB, 256, 0, stream>>>(off2, csr2, al2s8, al2s9, al2d, H2a, H2b, out);
}